// Round 13
// baseline (224.007 us; speedup 1.0000x reference)
//
#include <hip/hip_runtime.h>

typedef short bf16x8 __attribute__((ext_vector_type(8)));
typedef float floatx4 __attribute__((ext_vector_type(4)));
typedef float floatx2 __attribute__((ext_vector_type(2)));

typedef const __attribute__((address_space(1))) void* gas_ptr;
typedef __attribute__((address_space(3))) void* las_ptr;

#define EPB  4096   // edges per hist/scatter chunk
#define MAXB 6144   // bucket capacity (mean 4096, 32 sigma headroom)

__device__ __forceinline__ unsigned short f2bf(float f) {
    unsigned int u = __float_as_uint(f);
    unsigned int r = u + 0x7fffu + ((u >> 16) & 1u);   // RNE
    return (unsigned short)(r >> 16);
}

__device__ __forceinline__ void stage16(const void* g, void* lbase, int lane) {
#if __has_builtin(__builtin_amdgcn_global_load_lds)
    __builtin_amdgcn_global_load_lds((gas_ptr)g, (las_ptr)lbase, 16, 0, 0);
#else
    *(float4*)((char*)lbase + lane * 16) = *(const float4*)g;
#endif
}

// Fused prep: blocks [0,nb_conv) convert h->bf16; next nblkH blocks build the
// per-chunk coarse-bucket (dst>>8) LDS histogram -> gh[bin][blk]; last 128
// blocks transpose weights. No global atomics.
__global__ __launch_bounds__(256) void prep_all(
    const float* __restrict__ h, unsigned short* __restrict__ hbf, int nconv,
    const int* __restrict__ dst, int* __restrict__ gh, int E, int nB, int nblkH,
    const float* __restrict__ basis, const float* __restrict__ loopw,
    unsigned short* __restrict__ WT2, int nb_conv)
{
    __shared__ int lh[256];
    const int b = blockIdx.x;
    const int t = threadIdx.x;
    if (b < nb_conv) {
        int idx = b * 256 + t;
        if (idx < nconv) {
            float2 v = *(const float2*)(h + (size_t)idx * 2);
            unsigned int pack = (unsigned int)f2bf(v.x) | ((unsigned int)f2bf(v.y) << 16);
            *(unsigned int*)(hbf + (size_t)idx * 2) = pack;
        }
    } else if (b < nb_conv + nblkH) {
        const int blk = b - nb_conv;
        lh[t] = 0;
        __syncthreads();
        const int cbase = blk * EPB;
#pragma unroll
        for (int j = 0; j < EPB / 256; ++j) {
            int e = cbase + j * 256 + t;
            if (e < E) atomicAdd(&lh[dst[e] >> 8], 1);
        }
        __syncthreads();
        if (t < nB) gh[(size_t)t * nblkH + blk] = lh[t];
    } else {
        int c = b - nb_conv - nblkH;            // 0..127
        for (int k = t; k < 640; k += 256) {
            float v;
            if (k < 512) v = basis[(size_t)k * 128 + c];
            else         v = loopw[(size_t)(k - 512) * 128 + c];
            WT2[(size_t)c * 640 + k] = f2bf(v);
        }
    }
}

// Route edges into coarse buckets; cursors derived in-block from gh (self-scan).
// Block 0 publishes binStart. tmp packing: src(16) | rel<<16(7) | (dst&255)<<23(8).
__global__ __launch_bounds__(256) void scatter_bkt(
    const int* __restrict__ dst, const int* __restrict__ src,
    const int* __restrict__ rel, const int* __restrict__ gh,
    int* __restrict__ binStart, unsigned int* __restrict__ tmp,
    int E, int nB, int nblkH)
{
    __shared__ int ss[256];
    __shared__ int cur[256];
    const int j = blockIdx.x;
    const int t = threadIdx.x;

    int pre = 0, tot = 0;
    if (t < nB) {
        const int* row = gh + (size_t)t * nblkH;
#pragma unroll 8
        for (int c = 0; c < nblkH; ++c) {
            int v = row[c];
            tot += v;
            if (c < j) pre += v;
        }
    }
    int v = (t < nB) ? tot : 0;
    ss[t] = v;
    __syncthreads();
    for (int o = 1; o < 256; o <<= 1) {
        int x = (t >= o) ? ss[t - o] : 0;
        __syncthreads();
        ss[t] += x;
        __syncthreads();
    }
    const int gstart = ss[t] - v;
    cur[t] = gstart + pre;
    if (j == 0) {
        if (t < nB) binStart[t] = gstart;
        if (t == 0) binStart[nB] = E;
    }
    __syncthreads();

    const int cbase = j * EPB;
#pragma unroll
    for (int jj = 0; jj < EPB / 256; ++jj) {
        int e = cbase + jj * 256 + t;
        if (e < E) {
            int d = dst[e];
            int slot = atomicAdd(&cur[d >> 8], 1);
            tmp[slot] = (unsigned int)src[e] | ((unsigned int)rel[e] << 16)
                      | ((unsigned int)(d & 255) << 23);
        }
    }
}

// One block per bucket: finish sort by dst&255 in LDS, emit rowptr + sedge
// (packed src<<8 | rel<<25).
__global__ __launch_bounds__(256) void bucket_sort(
    const unsigned int* __restrict__ tmp, const int* __restrict__ binStart,
    unsigned int* __restrict__ sedge, int* __restrict__ rowptr,
    int E, int N, int nB)
{
    __shared__ unsigned int eb[MAXB];
    __shared__ int hh[256], ss[256], cur[256];
    const int b = blockIdx.x;
    const int t = threadIdx.x;
    const int brow = binStart[b];
    const int next = binStart[b + 1];
    int n = next - brow;
    if (n > MAXB) n = MAXB;
    hh[t] = 0;
    __syncthreads();
    for (int i = t; i < n; i += 256) {
        unsigned int v = tmp[brow + i];
        eb[i] = v;
        atomicAdd(&hh[(v >> 23) & 255], 1);
    }
    __syncthreads();
    int v = hh[t];
    ss[t] = v;
    __syncthreads();
    for (int o = 1; o < 256; o <<= 1) {
        int x = (t >= o) ? ss[t - o] : 0;
        __syncthreads();
        ss[t] += x;
        __syncthreads();
    }
    const int excl = ss[t] - v;
    const int idx = b * 256 + t;
    if (idx <= N) rowptr[idx] = brow + excl;
    cur[t] = excl;
    __syncthreads();
    for (int i = t; i < n; i += 256) {
        unsigned int e = eb[i];
        int slot = atomicAdd(&cur[(e >> 23) & 255], 1);
        sedge[brow + slot] = ((e & 0xFFFFu) << 8) | (((e >> 16) & 0x7Fu) << 25);
    }
}

// Split-wave aggregation: one wave per dst; lanes 0-31 process even-slot edges,
// lanes 32-63 odd-slot edges. Each lane gathers uint2 (4 dims) per edge ->
// half the gather instructions per edge (2x MLP). Halves combined via
// shfl_xor(32) once per dst; A2 layout unchanged.
__global__ __launch_bounds__(256) void aggregate_pre(
    const unsigned short* __restrict__ hbf,
    const int* __restrict__ rowptr,
    const unsigned int* __restrict__ sedge,
    const float* __restrict__ coeff,
    const float* __restrict__ norm,
    unsigned short* __restrict__ A2, int N, int R)
{
    __shared__ float scoef[512];               // R*4 <= 512
    for (int i = threadIdx.x; i < R * 4; i += 256) scoef[i] = coeff[i];
    __syncthreads();

    const int wave = threadIdx.x >> 6;
    const int lane = threadIdx.x & 63;
    const int half = lane >> 5;                // which edge of the pair
    const int l5   = lane & 31;                // dim group: 4*l5 .. 4*l5+3
    const int d = blockIdx.x * 4 + wave;
    if (d >= N) return;
    int i = rowptr[d];
    const int end = rowptr[d + 1];

    const char* hbase = (const char*)hbf + l5 * 8;   // uint2 per lane

    floatx2 a00 = {0.f,0.f}, a01 = {0.f,0.f}, a10 = {0.f,0.f}, a11 = {0.f,0.f};
    floatx2 a20 = {0.f,0.f}, a21 = {0.f,0.f}, a30 = {0.f,0.f}, a31 = {0.f,0.f};

#define SLOAD(v, g) uint2 g = *(const uint2*)(hbase + ((v) & 0x00FFFF00u));
#define SMATH(v, g) { \
    const float4 c = *(const float4*)((const char*)scoef + (((v) >> 25) << 4)); \
    floatx2 h0, h1; \
    h0[0] = __uint_as_float((g).x << 16); \
    h0[1] = __uint_as_float((g).x & 0xFFFF0000u); \
    h1[0] = __uint_as_float((g).y << 16); \
    h1[1] = __uint_as_float((g).y & 0xFFFF0000u); \
    a00 = __builtin_elementwise_fma((floatx2){c.x, c.x}, h0, a00); \
    a01 = __builtin_elementwise_fma((floatx2){c.x, c.x}, h1, a01); \
    a10 = __builtin_elementwise_fma((floatx2){c.y, c.y}, h0, a10); \
    a11 = __builtin_elementwise_fma((floatx2){c.y, c.y}, h1, a11); \
    a20 = __builtin_elementwise_fma((floatx2){c.z, c.z}, h0, a20); \
    a21 = __builtin_elementwise_fma((floatx2){c.z, c.z}, h1, a21); \
    a30 = __builtin_elementwise_fma((floatx2){c.w, c.w}, h0, a30); \
    a31 = __builtin_elementwise_fma((floatx2){c.w, c.w}, h1, a31); }

    // align i to 4 (for the uint4 edge-word loads below): <=1 single + <=1 pair
    if ((i & 1) && i < end) {                  // single edge, half 0 only
        if (half == 0) {
            unsigned int v = sedge[i];
            SLOAD(v, g) SMATH(v, g)
        }
        ++i;
    }
    if ((i & 2) && i + 2 <= end) {             // one pair
        unsigned int v = sedge[i + half];
        SLOAD(v, g) SMATH(v, g)
        i += 2;
    }
    // 16-edge blocks: each half does 8 edges via two aligned uint4 word loads
    for (; i + 16 <= end; i += 16) {
        uint4 w0 = *(const uint4*)(sedge + i + half * 4);       // edges i+4h..
        uint4 w1 = *(const uint4*)(sedge + i + 8 + half * 4);
        SLOAD(w0.x, g0) SLOAD(w0.y, g1) SLOAD(w0.z, g2) SLOAD(w0.w, g3)
        SLOAD(w1.x, g4) SLOAD(w1.y, g5) SLOAD(w1.z, g6) SLOAD(w1.w, g7)
        SMATH(w0.x, g0) SMATH(w0.y, g1) SMATH(w0.z, g2) SMATH(w0.w, g3)
        SMATH(w1.x, g4) SMATH(w1.y, g5) SMATH(w1.z, g6) SMATH(w1.w, g7)
    }
    for (; i + 2 <= end; i += 2) {             // pair steps
        unsigned int v = sedge[i + half];
        SLOAD(v, g) SMATH(v, g)
    }
    if (i < end && half == 0) {                // odd tail
        unsigned int v = sedge[i];
        SLOAD(v, g) SMATH(v, g)
    }
#undef SLOAD
#undef SMATH

    // combine halves
#define COMB(r) { r[0] += __shfl_xor(r[0], 32); r[1] += __shfl_xor(r[1], 32); }
    COMB(a00) COMB(a01) COMB(a10) COMB(a11)
    COMB(a20) COMB(a21) COMB(a30) COMB(a31)
#undef COMB

    if (half == 0) {
        const float nm = norm[d];
        unsigned short* row = A2 + (size_t)d * 512 + l5 * 4;
        uint2 p0, p1, p2, p3;
        p0.x = (unsigned int)f2bf(a00[0]*nm) | ((unsigned int)f2bf(a00[1]*nm) << 16);
        p0.y = (unsigned int)f2bf(a01[0]*nm) | ((unsigned int)f2bf(a01[1]*nm) << 16);
        p1.x = (unsigned int)f2bf(a10[0]*nm) | ((unsigned int)f2bf(a10[1]*nm) << 16);
        p1.y = (unsigned int)f2bf(a11[0]*nm) | ((unsigned int)f2bf(a11[1]*nm) << 16);
        p2.x = (unsigned int)f2bf(a20[0]*nm) | ((unsigned int)f2bf(a20[1]*nm) << 16);
        p2.y = (unsigned int)f2bf(a21[0]*nm) | ((unsigned int)f2bf(a21[1]*nm) << 16);
        p3.x = (unsigned int)f2bf(a30[0]*nm) | ((unsigned int)f2bf(a30[1]*nm) << 16);
        p3.y = (unsigned int)f2bf(a31[0]*nm) | ((unsigned int)f2bf(a31[1]*nm) << 16);
        *(uint2*)(row)       = p0;
        *(uint2*)(row + 128) = p1;
        *(uint2*)(row + 256) = p2;
        *(uint2*)(row + 384) = p3;
    }
}

// out = relu([A2 | h_bf] @ WT2^T): 64-row x 128-col tiles (782 blocks -> ~3
// blocks/CU, better staging/MFMA overlap than the 128-row version).
__global__ __launch_bounds__(256) void final_gemm(
    const unsigned short* __restrict__ A2,    // (N,512) bf16
    const unsigned short* __restrict__ hbf,   // (N,128) bf16
    const unsigned short* __restrict__ WT2,   // (128,640) bf16 [col][k]
    float* __restrict__ out, int N)
{
    __shared__ char sA[8192];    // [kc 0..7][row 0..63] x 16B
    __shared__ char sB[16384];   // [kc 0..7][col 0..127] x 16B
    const int t = threadIdx.x;
    const int w = t >> 6;
    const int lane = t & 63;
    const int quad = lane >> 4;
    const int low  = lane & 15;
    const int wr = w >> 1, wc = w & 1;   // 2x2 wave grid of 32x64 sub-tiles
    const int m0 = blockIdx.x * 64;

    floatx4 acc[2][4];
#pragma unroll
    for (int mt = 0; mt < 2; ++mt)
#pragma unroll
        for (int nt = 0; nt < 4; ++nt) acc[mt][nt] = (floatx4){0.f, 0.f, 0.f, 0.f};

    for (int it = 0; it < 10; ++it) {
        const int k0 = it * 64;
#pragma unroll
        for (int i = 0; i < 2; ++i) {          // A: 512 slots
            const int slot = i * 256 + t;
            const int kc  = slot >> 6;         // 0..7
            const int idx = slot & 63;
            int grow = m0 + idx;
            if (grow >= N) grow = N - 1;
            const unsigned short* gA = (k0 < 512)
                ? A2  + (size_t)grow * 512 + k0 + kc * 8
                : hbf + (size_t)grow * 128 + (k0 - 512) + kc * 8;
            stage16(gA, sA + (size_t)(i * 256 + w * 64) * 16, lane);
        }
#pragma unroll
        for (int i = 0; i < 4; ++i) {          // B: 1024 slots
            const int slot = i * 256 + t;
            const int kc  = slot >> 7;
            const int idx = slot & 127;
            const unsigned short* gB = WT2 + (size_t)idx * 640 + k0 + kc * 8;
            stage16(gB, sB + (size_t)(i * 256 + w * 64) * 16, lane);
        }
        __syncthreads();

#pragma unroll
        for (int ks = 0; ks < 2; ++ks) {
            bf16x8 af[2], bfr[4];
#pragma unroll
            for (int mt = 0; mt < 2; ++mt)
                af[mt] = *(const bf16x8*)(sA + (size_t)(((ks * 4 + quad) << 6) + wr * 32 + mt * 16 + low) * 16);
#pragma unroll
            for (int nt = 0; nt < 4; ++nt)
                bfr[nt] = *(const bf16x8*)(sB + (size_t)(((ks * 4 + quad) << 7) + wc * 64 + nt * 16 + low) * 16);
#pragma unroll
            for (int mt = 0; mt < 2; ++mt)
#pragma unroll
                for (int nt = 0; nt < 4; ++nt)
                    acc[mt][nt] = __builtin_amdgcn_mfma_f32_16x16x32_bf16(af[mt], bfr[nt], acc[mt][nt], 0, 0, 0);
        }
        __syncthreads();
    }

    // C/D: col=lane&15, row=(lane>>4)*4+reg
#pragma unroll
    for (int mt = 0; mt < 2; ++mt) {
#pragma unroll
        for (int nt = 0; nt < 4; ++nt) {
            const int c = wc * 64 + nt * 16 + low;
#pragma unroll
            for (int r = 0; r < 4; ++r) {
                int rr = m0 + wr * 32 + mt * 16 + quad * 4 + r;
                if (rr < N) out[(size_t)rr * 128 + c] = fmaxf(acc[mt][nt][r], 0.f);
            }
        }
    }
}

extern "C" void kernel_launch(void* const* d_in, const int* in_sizes, int n_in,
                              void* d_out, int out_size, void* d_ws, size_t ws_size,
                              hipStream_t stream)
{
    const float* h     = (const float*)d_in[0];
    const float* norm  = (const float*)d_in[1];
    const int*   src   = (const int*)d_in[2];
    const int*   dst   = (const int*)d_in[3];
    const int*   rel   = (const int*)d_in[4];
    const float* basis = (const float*)d_in[5];
    const float* coeff = (const float*)d_in[6];
    const float* loopw = (const float*)d_in[7];
    float* out = (float*)d_out;

    const int N = in_sizes[1];       // 50000
    const int E = in_sizes[2];       // 800000
    const int R = in_sizes[6] / 4;   // 100

    const int nB      = (N + 255) >> 8;          // 196 coarse buckets
    const int nblkH   = (E + EPB - 1) / EPB;     // 196 edge chunks
    const int M       = nB * nblkH;
    const int nb_conv = (N * 64 + 255) / 256;    // 12500

    char* ws = (char*)d_ws;
    size_t off = 0;
    auto walloc = [&](size_t bytes) -> char* {
        char* p = ws + off;
        off = (off + bytes + 255) & ~(size_t)255;
        return p;
    };
    unsigned short* A2       = (unsigned short*)walloc((size_t)N * 512 * 2);  // 51.2 MB
    unsigned short* hbf      = (unsigned short*)walloc((size_t)N * 128 * 2);  // 12.8 MB
    unsigned short* WT2      = (unsigned short*)walloc(128 * 640 * 2);
    int*            gh       = (int*)walloc((size_t)M * 4);
    int*            binStart = (int*)walloc((size_t)(nB + 1) * 4);
    unsigned int*   tmp      = (unsigned int*)walloc((size_t)E * 4);
    unsigned int*   sedge    = (unsigned int*)walloc((size_t)E * 4);
    int*            rowptr   = (int*)walloc((size_t)(N + 1) * 4);

    prep_all<<<nb_conv + nblkH + 128, 256, 0, stream>>>(
        h, hbf, N * 64, dst, gh, E, nB, nblkH, basis, loopw, WT2, nb_conv);
    scatter_bkt<<<nblkH, 256, 0, stream>>>(dst, src, rel, gh, binStart, tmp, E, nB, nblkH);
    bucket_sort<<<nB, 256, 0, stream>>>(tmp, binStart, sedge, rowptr, E, N, nB);
    aggregate_pre<<<(N + 3) / 4, 256, 0, stream>>>(hbf, rowptr, sedge, coeff, norm, A2, N, R);
    final_gemm<<<(N + 63) / 64, 256, 0, stream>>>(A2, hbf, WT2, out, N);
}